// Round 1
// baseline (1035.104 us; speedup 1.0000x reference)
//
#include <hip/hip_runtime.h>

// GroupedQueryAttention on MI355X (gfx950), round 9: key-split attention for
// occupancy. B=2, S=2048, E=2048, H=32, KVH=8, G=4, D=64.
// attn: 8 waves/block (512 thr). Waves 0-3 = 4 heads of the KV group over keys
// [0,1024); waves 4-7 = same heads over keys [1024,2048). Each key-half group
// has its own double-buffered K/V LDS pipeline (75.8 KB total -> 2 blocks/CU
// -> 4 waves/SIMD, up from 2). Max-free exp2 softmax means the two partials
// combine by pure addition: one in-LDS combine at the end (64 KB overlay).
// V tile stride 72 -> 76 shorts (38 dwords) kills the 2-way ds_read_b64 bank
// conflict (36*8 === 0 mod 32 before; 6c mod 32 spans all banks now).

typedef __attribute__((ext_vector_type(8)))  short     s16x8;
typedef __attribute__((ext_vector_type(8)))  _Float16  h8;
typedef __attribute__((ext_vector_type(2)))  __fp16    fp16x2;
typedef __attribute__((ext_vector_type(4)))  float     f32x4;
typedef __attribute__((ext_vector_type(16))) float     f32x16;

#define DEVI static __device__ __forceinline__

#if __has_builtin(__builtin_amdgcn_exp2f)
#define EXP2F __builtin_amdgcn_exp2f
#else
#define EXP2F exp2f
#endif

DEVI short f2h(float f){ _Float16 h = (_Float16)f; return __builtin_bit_cast(short, h); }
DEVI unsigned pkh(float a, float b){            // two f32 -> packed f16 (RTZ), 1 instr
  fp16x2 t = __builtin_amdgcn_cvt_pkrtz(a, b);
  return __builtin_bit_cast(unsigned, t);
}

typedef __attribute__((address_space(3))) unsigned       lds_u32;
typedef __attribute__((address_space(1))) const unsigned gbl_u32;
DEVI void glds16(const short* g, short* l){
  __builtin_amdgcn_global_load_lds((gbl_u32*)g, (lds_u32*)l, 16, 0, 0);
}

// ---------------- cast fp32 -> f16 ----------------
__global__ void cast_kernel(const float* __restrict__ in, short* __restrict__ out, int n){
  int i = (blockIdx.x * 256 + threadIdx.x) * 8;
  if(i >= n) return;
  float4 a = *(const float4*)(in + i);
  float4 b = *(const float4*)(in + i + 4);
  s16x8 v;
  v[0]=f2h(a.x); v[1]=f2h(a.y); v[2]=f2h(a.z); v[3]=f2h(a.w);
  v[4]=f2h(b.x); v[5]=f2h(b.y); v[6]=f2h(b.z); v[7]=f2h(b.w);
  *(s16x8*)(out + i) = v;
}

// ---------------- merged weight transposes (fp32 -> f16) + bias concat -------
// grid (32, 81): gy 0..31 Wq, 32..39 Wk, 40..47 Wv, 48..79 Wo, 80 bias concat
__global__ void prep_kernel(const float* __restrict__ Wq, const float* __restrict__ Wk,
                            const float* __restrict__ Wv, const float* __restrict__ Wo,
                            const float* __restrict__ bq, const float* __restrict__ bk,
                            const float* __restrict__ bv,
                            short* __restrict__ WT, short* __restrict__ WoT,
                            float* __restrict__ bqkv){
  __shared__ __align__(16) short tile[64*72];
  const int gy = blockIdx.y;
  const int t = threadIdx.x;
  if(gy >= 80){
    int i = blockIdx.x * 256 + t;
    if(i < 3072) bqkv[i] = (i < 2048) ? bq[i] : (i < 2560 ? bk[i-2048] : bv[i-2560]);
    return;
  }
  const float* src; short* dst; int ldin, by;
  if(gy < 32)      { src = Wq; dst = WT;             ldin = 2048; by = gy;    }
  else if(gy < 40) { src = Wk; dst = WT + 2048*2048; ldin =  512; by = gy-32; }
  else if(gy < 48) { src = Wv; dst = WT + 2560*2048; ldin =  512; by = gy-40; }
  else             { src = Wo; dst = WoT;            ldin = 2048; by = gy-48; }
  const int tr = blockIdx.x * 64;
  const int tc = by * 64;
  for(int c = t; c < 512; c += 256){
    int r = c >> 3, g = c & 7;
    const float* p = src + (size_t)(tr + r) * ldin + tc + g*8;
    s16x8 v;
    #pragma unroll
    for(int e = 0; e < 8; e++) v[e] = f2h(p[e]);
    *(s16x8*)&tile[r*72 + g*8] = v;
  }
  __syncthreads();
  for(int c = t; c < 512; c += 256){
    int r = c >> 3, g = c & 7;
    s16x8 v;
    #pragma unroll
    for(int e = 0; e < 8; e++) v[e] = tile[(g*8+e)*72 + r];
    *(s16x8*)(dst + (size_t)(tc + r) * 2048 + tr + g*8) = v;
  }
}

// ---------------- f16 transpose (for V^T) ----------------
__global__ void transpose_h_kernel(const short* __restrict__ in, short* __restrict__ out,
                                   int ldin, int ldout){
  __shared__ __align__(16) short tile[64*72];
  const int tr = blockIdx.x * 64;
  const int tc = blockIdx.y * 64;
  const int t = threadIdx.x;
  for(int c = t; c < 512; c += 256){
    int r = c >> 3, g = c & 7;
    *(s16x8*)&tile[r*72 + g*8] = *(const s16x8*)(in + (size_t)(tr + r) * ldin + tc + g*8);
  }
  __syncthreads();
  for(int c = t; c < 512; c += 256){
    int r = c >> 3, g = c & 7;
    s16x8 v;
    #pragma unroll
    for(int e = 0; e < 8; e++) v[e] = tile[(g*8+e)*72 + r];
    *(s16x8*)(out + (size_t)(tc + r) * ldout + tr + g*8) = v;
  }
}

// ---------------- GEMM (f16): C[M][N] = A[M][K] * BT[N][K]^T + bias[N] -------
template<bool OUT_F32>
__global__ __launch_bounds__(256, 2)
void gemm_bt_kernel(const short* __restrict__ A, const short* __restrict__ BT,
                    const float* __restrict__ bias, void* __restrict__ C,
                    int M, int N, int K, int scale_cols, float qscale){
  __shared__ __align__(16) short As[128*32];
  __shared__ __align__(16) short Bs[128*32];
  const int m0 = blockIdx.x * 128;
  const int n0 = blockIdx.y * 128;
  const int tid = threadIdx.x;
  const int wave = tid >> 6, lane = tid & 63;
  const int l16 = lane & 15, quad = lane >> 4;
  const int wm = (wave >> 1) * 64, wn = (wave & 1) * 64;

  const short* gA = A  + (size_t)(m0 + wave*32 + (lane>>2))*K + (lane&3)*8;
  const short* gB = BT + (size_t)(n0 + wave*32 + (lane>>2))*K + (lane&3)*8;
  short* lA = As + wave*32*32;
  short* lB = Bs + wave*32*32;

  f32x4 acc[4][4];
  #pragma unroll
  for(int i=0;i<4;i++)
    #pragma unroll
    for(int j=0;j<4;j++) acc[i][j] = (f32x4)(0.0f);

  for(int k0 = 0; k0 < K; k0 += 32){
    glds16(gA + k0,                lA);
    glds16(gA + 16*(size_t)K + k0, lA + 512);
    glds16(gB + k0,                lB);
    glds16(gB + 16*(size_t)K + k0, lB + 512);
    __syncthreads();
    h8 af[4], bfr[4];
    #pragma unroll
    for(int i=0;i<4;i++){
      af[i]  = *(const h8*)&As[(wm + i*16 + l16)*32 + quad*8];
      bfr[i] = *(const h8*)&Bs[(wn + i*16 + l16)*32 + quad*8];
    }
    #pragma unroll
    for(int i=0;i<4;i++)
      #pragma unroll
      for(int j=0;j<4;j++)
        acc[i][j] = __builtin_amdgcn_mfma_f32_16x16x32_f16(af[i], bfr[j], acc[i][j], 0, 0, 0);
    __syncthreads();
  }

  #pragma unroll
  for(int j=0;j<4;j++){
    int col = n0 + wn + j*16 + l16;
    float bb = bias[col];
    float sc = (col < scale_cols) ? qscale : 1.0f;
    #pragma unroll
    for(int i=0;i<4;i++){
      #pragma unroll
      for(int r=0;r<4;r++){
        size_t row = (size_t)(m0 + wm + i*16 + quad*4 + r);
        float v = (acc[i][j][r] + bb) * sc;
        if(OUT_F32) ((float*)C)[row*(size_t)N + col] = v;
        else        ((short*)C)[row*(size_t)N + col] = f2h(v);
      }
    }
  }
}

// ---------------- flash attention, key-split, register-P, 1 barrier/tile -----
// 8 waves; gw = wave>>2 picks key half [gw*1024, gw*1024+1024). Per group:
// independent double-buffered K/V staging (K stride 72, V stride 76 shorts).
// Per kb (32 keys): S^T = K*Q^T (32x32x16 f16), max-free exp2 softmax, P packed
// in-register as the PV B-operand; O^T accumulated in f32x16. Partials from the
// two key halves are summed in LDS (valid because softmax is max-free), then
// group 0 normalizes and stores.
#define KS_STRIDE 72
#define VS_STRIDE 76
#define GRP_SZ (64*KS_STRIDE + 64*VS_STRIDE)   // shorts per (group, buf)

__global__ __launch_bounds__(512, 4)
void attn_kernel(const short* __restrict__ Qg, const short* __restrict__ Kg,
                 const short* __restrict__ VT, short* __restrict__ Og, int ldq){
  const int qt  = blockIdx.x;    // 0..31 : 64-row q tile
  const int kvh = blockIdx.y;    // 0..7
  const int b   = blockIdx.z;    // 0..1
  const int tid = threadIdx.x;
  const int wave = tid >> 6, lane = tid & 63;
  const int gw = wave >> 2;      // key-half group
  const int w4 = wave & 3;       // head within group
  const int c = lane & 31, h = lane >> 5;
  const int head = kvh*4 + w4;
  const int q0 = qt * 64;

  __shared__ __align__(16) short smem[2*2*GRP_SZ];   // 75776 B

  // Q B-fragments (pre-scaled by 0.125*log2e in GEMM epilogue)
  h8 qreg[4][2];
  #pragma unroll
  for(int ks2=0; ks2<4; ks2++)
    #pragma unroll
    for(int qg=0; qg<2; qg++)
      qreg[ks2][qg] = *(const h8*)(Qg + (size_t)(b*2048 + q0 + qg*32 + c)*ldq
                                      + head*64 + ks2*16 + h*8);

  float lsum[2] = {0.0f, 0.0f};
  f32x16 oacc[2][2];               // [qg][mb]  O^T block: rows d, cols q
  #pragma unroll
  for(int qg=0; qg<2; qg++)
    #pragma unroll
    for(int mb=0; mb<2; mb++) oacc[qg][mb] = (f32x16)(0.0f);

  // staging: 256 threads per key-half (tid>>8 == gw); 16B chunk per thread,
  // rows (t8>>3) and (t8>>3)+32.
  const int t8 = tid & 255;
  const int kbase = gw * 1024;
  const short* gK = Kg + (size_t)(b*2048 + kbase + (t8>>3))*ldq + kvh*64 + (t8&7)*8;
  const short* gV = VT + (size_t)(kvh*64 + (t8>>3))*4096 + b*2048 + kbase + (t8&7)*8;
  const int soK = (t8>>3)*KS_STRIDE + (t8&7)*8;
  const int soV = (t8>>3)*VS_STRIDE + (t8&7)*8;
  const size_t kHalf = (size_t)32 * ldq;

  s16x8 kr0 = *(const s16x8*)(gK);
  s16x8 kr1 = *(const s16x8*)(gK + kHalf);
  s16x8 vr0 = *(const s16x8*)(gV);
  s16x8 vr1 = *(const s16x8*)(gV + 32*4096);

  for(int t0 = 0; t0 < 1024; t0 += 64){
    const int buf = (t0 >> 6) & 1;
    short* base = smem + (gw*2 + buf)*GRP_SZ;
    *(s16x8*)(base + soK)                     = kr0;
    *(s16x8*)(base + soK + 32*KS_STRIDE)      = kr1;
    *(s16x8*)(base + 64*KS_STRIDE + soV)                = vr0;
    *(s16x8*)(base + 64*KS_STRIDE + soV + 32*VS_STRIDE) = vr1;
    __syncthreads();                 // buf visible; prior readers of buf^1 done
    if(t0 + 64 < 1024){              // prefetch next tile (flies during compute)
      const short* nK = gK + (size_t)(t0 + 64)*ldq;
      const short* nV = gV + (t0 + 64);
      kr0 = *(const s16x8*)(nK);
      kr1 = *(const s16x8*)(nK + kHalf);
      vr0 = *(const s16x8*)(nV);
      vr1 = *(const s16x8*)(nV + 32*4096);
    }
    const short* Kbuf = smem + (gw*2 + buf)*GRP_SZ;
    const short* Vbuf = Kbuf + 64*KS_STRIDE;

    #pragma unroll
    for(int kb=0; kb<2; kb++){
      // S^T strip: keys kb*32..+31 x 64 q
      f32x16 st[2];
      st[0] = (f32x16)(0.0f); st[1] = (f32x16)(0.0f);
      #pragma unroll
      for(int ks2=0; ks2<4; ks2++){
        h8 ak = *(const h8*)&Kbuf[(kb*32 + c)*KS_STRIDE + ks2*16 + h*8];
        st[0] = __builtin_amdgcn_mfma_f32_32x32x16_f16(ak, qreg[ks2][0], st[0], 0, 0, 0);
        st[1] = __builtin_amdgcn_mfma_f32_32x32x16_f16(ak, qreg[ks2][1], st[1], 0, 0, 0);
      }

      // max-free softmax + in-register f16 pack (B-operand order = e order)
      union H8U { h8 v; unsigned u[4]; };
      H8U pk[2][2];                  // [qg][ksp]
      #pragma unroll
      for(int qg=0; qg<2; qg++){
        float sacc = 0.0f;
        #pragma unroll
        for(int j=0; j<4; j++){
          float pa = EXP2F(st[qg][2*j]);
          float pb = EXP2F(st[qg][2*j+1]);
          sacc += pa + pb;
          pk[qg][0].u[j] = pkh(pa, pb);
        }
        #pragma unroll
        for(int j=0; j<4; j++){
          float pa = EXP2F(st[qg][8+2*j]);
          float pb = EXP2F(st[qg][8+2*j+1]);
          sacc += pa + pb;
          pk[qg][1].u[j] = pkh(pa, pb);
        }
        lsum[qg] += sacc;
      }

      // O^T += V * P^T ; V A-frag at kappa offsets: {h*4+0..3, 8+h*4+0..3}
      #pragma unroll
      for(int ksp=0; ksp<2; ksp++){
        #pragma unroll
        for(int mb=0; mb<2; mb++){
          const short* vb = &Vbuf[(mb*32 + c)*VS_STRIDE + kb*32 + ksp*16 + h*4];
          H8U av;
          *(uint2*)&av.u[0] = *(const uint2*)(vb);
          *(uint2*)&av.u[2] = *(const uint2*)(vb + 8);
          oacc[0][mb] = __builtin_amdgcn_mfma_f32_32x32x16_f16(av.v, pk[0][ksp].v, oacc[0][mb], 0, 0, 0);
          oacc[1][mb] = __builtin_amdgcn_mfma_f32_32x32x16_f16(av.v, pk[1][ksp].v, oacc[1][mb], 0, 0, 0);
        }
      }
    }
  }

  // ---- combine the two key-half partials (pure sums: max-free softmax) ----
  __syncthreads();                        // all K/V tile reads done; smem reusable
  float* comb  = (float*)smem;            // [w4][16 quads][64 lanes] f32x4 = 64 KiB
  float* lcomb = (float*)smem + 16384;    // [w4][2][64] f32 = 2 KiB
  if(gw == 1){
    #pragma unroll
    for(int qg=0; qg<2; qg++){
      lcomb[(w4*2 + qg)*64 + lane] = lsum[qg];
      #pragma unroll
      for(int mb=0; mb<2; mb++){
        #pragma unroll
        for(int g2=0; g2<4; g2++){
          f32x4 q4;
          q4[0] = oacc[qg][mb][4*g2+0]; q4[1] = oacc[qg][mb][4*g2+1];
          q4[2] = oacc[qg][mb][4*g2+2]; q4[3] = oacc[qg][mb][4*g2+3];
          *(f32x4*)&comb[(((w4*4 + qg*2 + mb)*4 + g2)*64 + lane)*4] = q4;
        }
      }
    }
  }
  __syncthreads();
  if(gw == 1) return;
  #pragma unroll
  for(int qg=0; qg<2; qg++){
    lsum[qg] += lcomb[(w4*2 + qg)*64 + lane];
    #pragma unroll
    for(int mb=0; mb<2; mb++){
      #pragma unroll
      for(int g2=0; g2<4; g2++){
        f32x4 q4 = *(const f32x4*)&comb[(((w4*4 + qg*2 + mb)*4 + g2)*64 + lane)*4];
        oacc[qg][mb][4*g2+0] += q4[0]; oacc[qg][mb][4*g2+1] += q4[1];
        oacc[qg][mb][4*g2+2] += q4[2]; oacc[qg][mb][4*g2+3] += q4[3];
      }
    }
  }

  // normalize + store: O^T C-layout -> lane owns q = q0+qg*32+c,
  // d = mb*32 + (e&3) + 8*(e>>2) + 4h  (4 consecutive d per e-quad -> b64)
  #pragma unroll
  for(int qg=0; qg<2; qg++){
    lsum[qg] += __shfl_xor(lsum[qg], 32);
    float li = 1.0f / lsum[qg];
    size_t rowoff = (size_t)(b*2048 + q0 + qg*32 + c)*2048 + head*64;
    #pragma unroll
    for(int mb=0; mb<2; mb++){
      #pragma unroll
      for(int g2=0; g2<4; g2++){
        int d0 = mb*32 + 8*g2 + 4*h;
        uint2 wv;
        wv.x = pkh(oacc[qg][mb][4*g2+0]*li, oacc[qg][mb][4*g2+1]*li);
        wv.y = pkh(oacc[qg][mb][4*g2+2]*li, oacc[qg][mb][4*g2+3]*li);
        *(uint2*)&Og[rowoff + d0] = wv;
      }
    }
  }
}

extern "C" void kernel_launch(void* const* d_in, const int* in_sizes, int n_in,
                              void* d_out, int out_size, void* d_ws, size_t ws_size,
                              hipStream_t stream){
  const float* x  = (const float*)d_in[0];
  const float* Wq = (const float*)d_in[1];
  const float* bq = (const float*)d_in[2];
  const float* Wk = (const float*)d_in[3];
  const float* bk = (const float*)d_in[4];
  const float* Wv = (const float*)d_in[5];
  const float* bv = (const float*)d_in[6];
  const float* Wo = (const float*)d_in[7];
  const float* bo = (const float*)d_in[8];

  char* ws = (char*)d_ws;
  short* WT   = (short*)(ws);                 // [3072][2048] f16
  short* WoT  = (short*)(ws + 25165824);      // [2048][2048] f16
  short* xb   = (short*)(ws + 33554432);      // [4096][2048] f16
  short* QKV  = (short*)(ws + 50331648);      // [4096][3072] f16
  short* VTb  = (short*)(ws + 75497472);      // [512][4096]  f16
  float* bqkv = (float*)(ws + 79691776);      // [3072]
  short* AO   = xb;                           // xb dead after QKV GEMM

  cast_kernel<<<4096, 256, 0, stream>>>(x, xb, 8388608);
  prep_kernel<<<dim3(32,81), 256, 0, stream>>>(Wq, Wk, Wv, Wo, bq, bk, bv, WT, WoT, bqkv);

  // QKV projection; Q columns pre-scaled by 1/sqrt(64)*log2(e) for exp2 softmax
  gemm_bt_kernel<false><<<dim3(32,24), 256, 0, stream>>>(xb, WT, bqkv, QKV,
                                                         4096, 3072, 2048,
                                                         2048, 0.1803368801111244f);

  transpose_h_kernel<<<dim3(64,8), 256, 0, stream>>>(QKV + 2560, VTb, 3072, 4096);

  attn_kernel<<<dim3(32,8,2), 512, 0, stream>>>(QKV, QKV + 2048, VTb, AO, 3072);

  gemm_bt_kernel<true><<<dim3(32,16), 256, 0, stream>>>(AO, WoT, bo, (float*)d_out,
                                                        4096, 2048, 2048, 0, 1.0f);
}

// Round 2
// 317.196 us; speedup vs baseline: 3.2633x; 3.2633x over previous
//
#include <hip/hip_runtime.h>

// GroupedQueryAttention on MI355X (gfx950), round 10: LDS-free attention.
// B=2, S=2048, E=2048, H=32, KVH=8, G=4, D=64.
// Round-9 post-mortem: launch_bounds(512,4) capped VGPRs at 128 -> accumulator
// spill -> 3.8 GB scratch traffic, 10x regression. Occupancy cannot be raised
// with this per-wave state; instead remove the LDS middleman:
//   - fragpack_kernel pre-packs K and V into exact MFMA A-fragment order in
//     global memory (lane-contiguous 16B chunks, streams are fully sequential).
//   - attn_kernel: no LDS, no barriers. Each wave streams K/V frags with
//     coalesced global_load_dwordx4, register double-buffered one half-tile
//     (32 keys) ahead. XCD-aware block swizzle keeps each XCD's working set
//     to 2 (b,kvh) groups = 1 MB -> L2-resident fragment traffic.
// Round-6 lesson respected: global frag loads are only catastrophic when
// UNSWIZZLED (32 lines/instr); pre-swizzled frags are 1 line/instr.

typedef __attribute__((ext_vector_type(8)))  short     s16x8;
typedef __attribute__((ext_vector_type(8)))  _Float16  h8;
typedef __attribute__((ext_vector_type(2)))  __fp16    fp16x2;
typedef __attribute__((ext_vector_type(4)))  float     f32x4;
typedef __attribute__((ext_vector_type(16))) float     f32x16;

#define DEVI static __device__ __forceinline__

#if __has_builtin(__builtin_amdgcn_exp2f)
#define EXP2F __builtin_amdgcn_exp2f
#else
#define EXP2F exp2f
#endif

DEVI short f2h(float f){ _Float16 h = (_Float16)f; return __builtin_bit_cast(short, h); }
DEVI unsigned pkh(float a, float b){            // two f32 -> packed f16 (RTZ), 1 instr
  fp16x2 t = __builtin_amdgcn_cvt_pkrtz(a, b);
  return __builtin_bit_cast(unsigned, t);
}

typedef __attribute__((address_space(3))) unsigned       lds_u32;
typedef __attribute__((address_space(1))) const unsigned gbl_u32;
DEVI void glds16(const short* g, short* l){
  __builtin_amdgcn_global_load_lds((gbl_u32*)g, (lds_u32*)l, 16, 0, 0);
}

// ---------------- cast fp32 -> f16 ----------------
__global__ void cast_kernel(const float* __restrict__ in, short* __restrict__ out, int n){
  int i = (blockIdx.x * 256 + threadIdx.x) * 8;
  if(i >= n) return;
  float4 a = *(const float4*)(in + i);
  float4 b = *(const float4*)(in + i + 4);
  s16x8 v;
  v[0]=f2h(a.x); v[1]=f2h(a.y); v[2]=f2h(a.z); v[3]=f2h(a.w);
  v[4]=f2h(b.x); v[5]=f2h(b.y); v[6]=f2h(b.z); v[7]=f2h(b.w);
  *(s16x8*)(out + i) = v;
}

// ---------------- merged weight transposes (fp32 -> f16) + bias concat -------
// grid (32, 81): gy 0..31 Wq, 32..39 Wk, 40..47 Wv, 48..79 Wo, 80 bias concat
__global__ void prep_kernel(const float* __restrict__ Wq, const float* __restrict__ Wk,
                            const float* __restrict__ Wv, const float* __restrict__ Wo,
                            const float* __restrict__ bq, const float* __restrict__ bk,
                            const float* __restrict__ bv,
                            short* __restrict__ WT, short* __restrict__ WoT,
                            float* __restrict__ bqkv){
  __shared__ __align__(16) short tile[64*72];
  const int gy = blockIdx.y;
  const int t = threadIdx.x;
  if(gy >= 80){
    int i = blockIdx.x * 256 + t;
    if(i < 3072) bqkv[i] = (i < 2048) ? bq[i] : (i < 2560 ? bk[i-2048] : bv[i-2560]);
    return;
  }
  const float* src; short* dst; int ldin, by;
  if(gy < 32)      { src = Wq; dst = WT;             ldin = 2048; by = gy;    }
  else if(gy < 40) { src = Wk; dst = WT + 2048*2048; ldin =  512; by = gy-32; }
  else if(gy < 48) { src = Wv; dst = WT + 2560*2048; ldin =  512; by = gy-40; }
  else             { src = Wo; dst = WoT;            ldin = 2048; by = gy-48; }
  const int tr = blockIdx.x * 64;
  const int tc = by * 64;
  for(int c = t; c < 512; c += 256){
    int r = c >> 3, g = c & 7;
    const float* p = src + (size_t)(tr + r) * ldin + tc + g*8;
    s16x8 v;
    #pragma unroll
    for(int e = 0; e < 8; e++) v[e] = f2h(p[e]);
    *(s16x8*)&tile[r*72 + g*8] = v;
  }
  __syncthreads();
  for(int c = t; c < 512; c += 256){
    int r = c >> 3, g = c & 7;
    s16x8 v;
    #pragma unroll
    for(int e = 0; e < 8; e++) v[e] = tile[(g*8+e)*72 + r];
    *(s16x8*)(dst + (size_t)(tc + r) * 2048 + tr + g*8) = v;
  }
}

// ---------------- GEMM (f16): C[M][N] = A[M][K] * BT[N][K]^T + bias[N] -------
template<bool OUT_F32>
__global__ __launch_bounds__(256, 2)
void gemm_bt_kernel(const short* __restrict__ A, const short* __restrict__ BT,
                    const float* __restrict__ bias, void* __restrict__ C,
                    int M, int N, int K, int scale_cols, float qscale){
  __shared__ __align__(16) short As[128*32];
  __shared__ __align__(16) short Bs[128*32];
  const int m0 = blockIdx.x * 128;
  const int n0 = blockIdx.y * 128;
  const int tid = threadIdx.x;
  const int wave = tid >> 6, lane = tid & 63;
  const int l16 = lane & 15, quad = lane >> 4;
  const int wm = (wave >> 1) * 64, wn = (wave & 1) * 64;

  const short* gA = A  + (size_t)(m0 + wave*32 + (lane>>2))*K + (lane&3)*8;
  const short* gB = BT + (size_t)(n0 + wave*32 + (lane>>2))*K + (lane&3)*8;
  short* lA = As + wave*32*32;
  short* lB = Bs + wave*32*32;

  f32x4 acc[4][4];
  #pragma unroll
  for(int i=0;i<4;i++)
    #pragma unroll
    for(int j=0;j<4;j++) acc[i][j] = (f32x4)(0.0f);

  for(int k0 = 0; k0 < K; k0 += 32){
    glds16(gA + k0,                lA);
    glds16(gA + 16*(size_t)K + k0, lA + 512);
    glds16(gB + k0,                lB);
    glds16(gB + 16*(size_t)K + k0, lB + 512);
    __syncthreads();
    h8 af[4], bfr[4];
    #pragma unroll
    for(int i=0;i<4;i++){
      af[i]  = *(const h8*)&As[(wm + i*16 + l16)*32 + quad*8];
      bfr[i] = *(const h8*)&Bs[(wn + i*16 + l16)*32 + quad*8];
    }
    #pragma unroll
    for(int i=0;i<4;i++)
      #pragma unroll
      for(int j=0;j<4;j++)
        acc[i][j] = __builtin_amdgcn_mfma_f32_16x16x32_f16(af[i], bfr[j], acc[i][j], 0, 0, 0);
    __syncthreads();
  }

  #pragma unroll
  for(int j=0;j<4;j++){
    int col = n0 + wn + j*16 + l16;
    float bb = bias[col];
    float sc = (col < scale_cols) ? qscale : 1.0f;
    #pragma unroll
    for(int i=0;i<4;i++){
      #pragma unroll
      for(int r=0;r<4;r++){
        size_t row = (size_t)(m0 + wm + i*16 + quad*4 + r);
        float v = (acc[i][j][r] + bb) * sc;
        if(OUT_F32) ((float*)C)[row*(size_t)N + col] = v;
        else        ((short*)C)[row*(size_t)N + col] = f2h(v);
      }
    }
  }
}

// ---------------- K/V fragment pre-pack ----------------
// grid (32 tiles, 8 kvh, 2 b), 256 thr. Reads the K and V column slices of
// QKV for one 64-key tile into LDS, emits MFMA A-fragment-ordered chunks:
//   Kf chunk (t,kb,ks2,l):  K[t*64+kb*32+(l&31)][ks2*16+(l>>5)*8 .. +8]
//   Vf chunk (t,kb,ksp,mb,l): keys k0..k0+3, k0+8..k0+11 (k0=kb*32+ksp*16+(l>>5)*4)
//                             at d = mb*32+(l&31)   (the PV kappa order)
// Chunk index within a tile == the lane that will read it -> attn loads are
// lane-contiguous global_load_dwordx4 and the stream is fully sequential.
__global__ void fragpack_kernel(const short* __restrict__ QKV,
                                short* __restrict__ Kf, short* __restrict__ Vf){
  __shared__ __align__(16) short kt[64*72];
  __shared__ __align__(16) short vt[64*72];
  const int t = blockIdx.x, kvh = blockIdx.y, b = blockIdx.z;
  const int tid = threadIdx.x;
  const size_t rowbase = (size_t)(b*2048 + t*64);
  for(int c = tid; c < 512; c += 256){
    int r = c >> 3, g = c & 7;
    const short* src = QKV + (rowbase + r)*3072 + kvh*64 + g*8;
    *(s16x8*)&kt[r*72 + g*8] = *(const s16x8*)(src + 2048);
    *(s16x8*)&vt[r*72 + g*8] = *(const s16x8*)(src + 2560);
  }
  __syncthreads();
  const size_t obase = ((size_t)(b*8 + kvh)*32 + t) * 4096;
  for(int ch = tid; ch < 512; ch += 256){
    int kb = ch >> 8, l = ch & 63;
    int c = l & 31, h = l >> 5;
    // K chunk: ch = kb*256 + ks2*64 + l
    int ks2 = (ch >> 6) & 3;
    *(s16x8*)(Kf + obase + (size_t)ch*8) =
        *(const s16x8*)&kt[(kb*32 + c)*72 + ks2*16 + h*8];
    // V chunk: ch = kb*256 + ksp*128 + mb*64 + l
    int ksp = (ch >> 7) & 1, mb = (ch >> 6) & 1;
    int k0 = kb*32 + ksp*16 + h*4;
    int d  = mb*32 + c;
    s16x8 v;
    #pragma unroll
    for(int j = 0; j < 4; j++){
      v[j]   = vt[(k0 + j)*72 + d];
      v[4+j] = vt[(k0 + 8 + j)*72 + d];
    }
    *(s16x8*)(Vf + obase + (size_t)ch*8) = v;
  }
}

// ---------------- flash attention: LDS-free, global frag streams ----------
// 512 blocks (XCD-swizzled) x 4 waves (= 4 heads of one KV group, 64-row
// q-tile). Per half-tile (32 keys): 8 coalesced b128 frag loads (K 4, V 4),
// S^T = K*Q^T (32x32x16 f16), max-free exp2 softmax packed in-register as the
// PV B-operand, O^T accumulated in f32x16. Register double buffer: frags for
// half-tile it+1 are issued before computing it. No LDS, no barriers.
__global__ __launch_bounds__(256, 2)
void attn_kernel(const short* __restrict__ Qg, const short* __restrict__ Kf,
                 const short* __restrict__ Vf, short* __restrict__ Og, int ldq){
  const int L = blockIdx.x;
  const int nid = (L & 7)*64 + (L >> 3);   // XCD swizzle: XCD x owns nid [x*64, x*64+64)
  const int qt  = nid & 31;                // 64-row q tile
  const int grp = nid >> 5;                // = b*8 + kvh  (2 groups per XCD -> 1 MB in L2)
  const int kvh = grp & 7, b = grp >> 3;
  const int tid = threadIdx.x;
  const int wave = tid >> 6, lane = tid & 63;
  const int c = lane & 31, h = lane >> 5;
  const int head = kvh*4 + wave;
  const int q0 = qt * 64;

  // Q B-fragments (pre-scaled by 0.125*log2e in GEMM epilogue)
  h8 qreg[4][2];
  #pragma unroll
  for(int ks2=0; ks2<4; ks2++)
    #pragma unroll
    for(int qg=0; qg<2; qg++)
      qreg[ks2][qg] = *(const h8*)(Qg + (size_t)(b*2048 + q0 + qg*32 + c)*ldq
                                      + head*64 + ks2*16 + h*8);

  float lsum[2] = {0.0f, 0.0f};
  f32x16 oacc[2][2];               // [qg][mb]  O^T block: rows d, cols q
  #pragma unroll
  for(int qg=0; qg<2; qg++)
    #pragma unroll
    for(int mb=0; mb<2; mb++) oacc[qg][mb] = (f32x16)(0.0f);

  const short* kp = Kf + (size_t)grp * 131072 + lane*8;
  const short* vp = Vf + (size_t)grp * 131072 + lane*8;

  h8 kA[4], vA[4], kB[4], vB[4];

  auto loadf = [&](size_t it, h8* K, h8* V){
    const short* kq = kp + it*2048;
    const short* vq = vp + it*2048;
    #pragma unroll
    for(int i=0;i<4;i++){
      K[i] = *(const h8*)(kq + i*512);
      V[i] = *(const h8*)(vq + i*512);
    }
  };

  auto compute = [&](const h8* K, const h8* V){
    f32x16 st[2];
    st[0] = (f32x16)(0.0f); st[1] = (f32x16)(0.0f);
    #pragma unroll
    for(int ks2=0; ks2<4; ks2++){
      st[0] = __builtin_amdgcn_mfma_f32_32x32x16_f16(K[ks2], qreg[ks2][0], st[0], 0, 0, 0);
      st[1] = __builtin_amdgcn_mfma_f32_32x32x16_f16(K[ks2], qreg[ks2][1], st[1], 0, 0, 0);
    }
    union H8U { h8 v; unsigned u[4]; };
    H8U pk[2][2];                  // [qg][ksp]
    #pragma unroll
    for(int qg=0; qg<2; qg++){
      float sacc = 0.0f;
      #pragma unroll
      for(int j=0; j<4; j++){
        float pa = EXP2F(st[qg][2*j]);
        float pb = EXP2F(st[qg][2*j+1]);
        sacc += pa + pb;
        pk[qg][0].u[j] = pkh(pa, pb);
      }
      #pragma unroll
      for(int j=0; j<4; j++){
        float pa = EXP2F(st[qg][8+2*j]);
        float pb = EXP2F(st[qg][8+2*j+1]);
        sacc += pa + pb;
        pk[qg][1].u[j] = pkh(pa, pb);
      }
      lsum[qg] += sacc;
    }
    #pragma unroll
    for(int ksp=0; ksp<2; ksp++){
      #pragma unroll
      for(int mb=0; mb<2; mb++){
        oacc[0][mb] = __builtin_amdgcn_mfma_f32_32x32x16_f16(V[ksp*2+mb], pk[0][ksp].v, oacc[0][mb], 0, 0, 0);
        oacc[1][mb] = __builtin_amdgcn_mfma_f32_32x32x16_f16(V[ksp*2+mb], pk[1][ksp].v, oacc[1][mb], 0, 0, 0);
      }
    }
  };

  loadf(0, kA, vA);
  #pragma unroll 1
  for(int it = 0; it < 64; it += 2){
    loadf((size_t)(it+1), kB, vB);
    compute(kA, vA);
    loadf((size_t)(it+2 < 64 ? it+2 : 0), kA, vA);
    compute(kB, vB);
  }

  // normalize + store: O^T C-layout -> lane owns q = q0+qg*32+c,
  // d = mb*32 + (e&3) + 8*(e>>2) + 4h  (4 consecutive d per e-quad -> b64)
  #pragma unroll
  for(int qg=0; qg<2; qg++){
    lsum[qg] += __shfl_xor(lsum[qg], 32);
    float li = 1.0f / lsum[qg];
    size_t rowoff = (size_t)(b*2048 + q0 + qg*32 + c)*2048 + head*64;
    #pragma unroll
    for(int mb=0; mb<2; mb++){
      #pragma unroll
      for(int g2=0; g2<4; g2++){
        int d0 = mb*32 + 8*g2 + 4*h;
        uint2 wv;
        wv.x = pkh(oacc[qg][mb][4*g2+0]*li, oacc[qg][mb][4*g2+1]*li);
        wv.y = pkh(oacc[qg][mb][4*g2+2]*li, oacc[qg][mb][4*g2+3]*li);
        *(uint2*)&Og[rowoff + d0] = wv;
      }
    }
  }
}

extern "C" void kernel_launch(void* const* d_in, const int* in_sizes, int n_in,
                              void* d_out, int out_size, void* d_ws, size_t ws_size,
                              hipStream_t stream){
  const float* x  = (const float*)d_in[0];
  const float* Wq = (const float*)d_in[1];
  const float* bq = (const float*)d_in[2];
  const float* Wk = (const float*)d_in[3];
  const float* bk = (const float*)d_in[4];
  const float* Wv = (const float*)d_in[5];
  const float* bv = (const float*)d_in[6];
  const float* Wo = (const float*)d_in[7];
  const float* bo = (const float*)d_in[8];

  char* ws = (char*)d_ws;
  short* WT   = (short*)(ws);                 // [3072][2048] f16 (dead after QKV GEMM)
  short* WoT  = (short*)(ws + 25165824);      // [2048][2048] f16
  short* xb   = (short*)(ws + 33554432);      // [4096][2048] f16
  short* QKV  = (short*)(ws + 50331648);      // [4096][3072] f16
  float* bqkv = (float*)(ws + 79691776);      // [3072]
  short* AO   = xb;                           // xb dead after QKV GEMM
  short* Kf   = (short*)(ws);                 // [16][131072] f16 frag-packed K (over dead WT)
  short* Vf   = (short*)(ws + 4194304);       // [16][131072] f16 frag-packed V (over dead WT)

  cast_kernel<<<4096, 256, 0, stream>>>(x, xb, 8388608);
  prep_kernel<<<dim3(32,81), 256, 0, stream>>>(Wq, Wk, Wv, Wo, bq, bk, bv, WT, WoT, bqkv);

  // QKV projection; Q columns pre-scaled by 1/sqrt(64)*log2(e) for exp2 softmax
  gemm_bt_kernel<false><<<dim3(32,24), 256, 0, stream>>>(xb, WT, bqkv, QKV,
                                                         4096, 3072, 2048,
                                                         2048, 0.1803368801111244f);

  fragpack_kernel<<<dim3(32,8,2), 256, 0, stream>>>(QKV, Kf, Vf);

  attn_kernel<<<512, 256, 0, stream>>>(QKV, Kf, Vf, AO, 3072);

  gemm_bt_kernel<true><<<dim3(32,16), 256, 0, stream>>>(AO, WoT, bo, (float*)d_out,
                                                        4096, 2048, 2048, 0, 1.0f);
}